// Round 9
// baseline (34.337 us; speedup 1.0000x reference)
//
#include <hip/hip_runtime.h>

#define ALPHA 0.5f
#define NCLS 86
#define FEAT 256
#define NTOT 131072

constexpr int K  = 128;         // sample chunks
constexpr int CH = NTOT / K;    // 1024 samples per chunk (one wave each)
constexpr int L4 = CH / 4;      // 256 int4 label-packs per chunk

// ws layout (floats):
//   S_part   [NCLS][K][FEAT]  = 2818048
//   cnt_part [NCLS][K]        = 11008
//   l2_part  [NCLS][K]        = 11008
//   loss_acc                  = 1
//   done (int)                = 1
constexpr size_t WS_S    = 0;
constexpr size_t WS_CNT  = (size_t)NCLS * K * FEAT;
constexpr size_t WS_L2   = WS_CNT + (size_t)NCLS * K;
constexpr size_t WS_LOSS = WS_L2 + (size_t)NCLS * K;
constexpr size_t WS_DONE = WS_LOSS + 1;

// 128-thread blocks (2 waves): 5504 blocks; VGPR<64, no LDS -> 16 blocks/CU
// (32 waves/CU) co-resident, remainder backfills -> smooth tail.
__global__ __launch_bounds__(128) void ctc_main(
    const float4* __restrict__ feat4, const int4* __restrict__ lab4,
    float4* __restrict__ S_part4, float* __restrict__ cnt_part,
    float* __restrict__ l2_part, float* __restrict__ loss_acc,
    int* __restrict__ done)
{
    if (threadIdx.x == 0) { *loss_acc = 0.f; *done = 0; }  // all blocks write same values

    const int wave = threadIdx.x >> 6;
    const int lane = threadIdx.x & 63;
    const int pair = blockIdx.x * 2 + wave;   // = c*K + k
    const int k = pair & (K - 1);
    const int c = pair / K;
    const int base = k * CH;                  // first sample of this chunk

    const int4* lp = lab4 + (base >> 2) + lane;
    // dummy row for empty-mask slots: chunk's own row 0 (L2-hot after 1st touch)
    const size_t dummy = (size_t)base * 64 + lane;

    float4 acc = {0.f, 0.f, 0.f, 0.f};
    float  acc2 = 0.f;
    int    cnt  = 0;   // wave-uniform (ballot popcounts)

    int4 L = lp[0];    // prefetched labels for current iteration
    for (int it = 0; it < L4; it += 64) {
        const int4 Lc = L;
        if (it + 64 < L4) L = lp[it + 64];    // prefetch next iter's labels
        unsigned long long m0 = __ballot(Lc.x == c);
        unsigned long long m1 = __ballot(Lc.y == c);
        unsigned long long m2 = __ballot(Lc.z == c);
        unsigned long long m3 = __ballot(Lc.w == c);
        cnt += __popcll(m0) + __popcll(m1) + __popcll(m2) + __popcll(m3);

        // cross-mask 4-wide drain: pop one bit from EACH mask per trip and
        // issue all 4 row-loads before any accumulate (~3 useful loads in
        // flight typical; empty slots re-read the L2-hot dummy row).
#define ACCUM(v)                                                           \
        { acc.x += v.x; acc.y += v.y; acc.z += v.z; acc.w += v.w;          \
          acc2  += v.x * v.x + v.y * v.y + v.z * v.z + v.w * v.w; }
        while (m0 | m1 | m2 | m3) {
            const bool h0 = m0 != 0, h1 = m1 != 0, h2 = m2 != 0, h3 = m3 != 0;
            const int b0 = (int)__ffsll((long long)m0) - 1;
            const int b1 = (int)__ffsll((long long)m1) - 1;
            const int b2 = (int)__ffsll((long long)m2) - 1;
            const int b3 = (int)__ffsll((long long)m3) - 1;
            m0 &= m0 - 1; m1 &= m1 - 1; m2 &= m2 - 1; m3 &= m3 - 1;
            const float4 v0 = feat4[h0 ? (size_t)(base + (it + b0) * 4 + 0) * 64 + lane : dummy];
            const float4 v1 = feat4[h1 ? (size_t)(base + (it + b1) * 4 + 1) * 64 + lane : dummy];
            const float4 v2 = feat4[h2 ? (size_t)(base + (it + b2) * 4 + 2) * 64 + lane : dummy];
            const float4 v3 = feat4[h3 ? (size_t)(base + (it + b3) * 4 + 3) * 64 + lane : dummy];
            if (h0) ACCUM(v0)
            if (h1) ACCUM(v1)
            if (h2) ACCUM(v2)
            if (h3) ACCUM(v3)
        }
#undef ACCUM
    }

    // acc holds features 4*lane .. 4*lane+3 -> write partial row directly
    S_part4[(size_t)pair * 64 + lane] = acc;

    for (int off = 32; off; off >>= 1)
        acc2 += __shfl_down(acc2, off, 64);
    if (lane == 0) {
        cnt_part[pair] = (float)cnt;
        l2_part[pair]  = acc2;
    }
}

__global__ __launch_bounds__(1024) void ctc_finalize(
    const float* __restrict__ centers, const float* __restrict__ S_part,
    const float* __restrict__ cnt_part, const float* __restrict__ l2_part,
    float* __restrict__ loss_acc, int* __restrict__ done,
    float* __restrict__ out)   // out[0] = loss, out+1 = new centers
{
    const int c  = blockIdx.x;
    const int t  = threadIdx.x & 255;
    const int kq = threadIdx.x >> 8;     // 0..3, k-quarter

    float S = 0.f;
#pragma unroll
    for (int j = 0; j < K / 4; ++j)
        S += S_part[((size_t)c * K + kq * (K / 4) + j) * FEAT + t];

    __shared__ float red[4][FEAT];
    __shared__ float r2[4];
    __shared__ float sn_s, sl2_s;
    red[kq][t] = S;

    // counts & l2 partials: 128 values -> 2 per lane of wave 0
    if (threadIdx.x < 64) {
        float a = cnt_part[c * K + threadIdx.x] + cnt_part[c * K + 64 + threadIdx.x];
        float b = l2_part[c * K + threadIdx.x]  + l2_part[c * K + 64 + threadIdx.x];
        for (int off = 32; off; off >>= 1) {
            a += __shfl_down(a, off, 64);
            b += __shfl_down(b, off, 64);
        }
        if (threadIdx.x == 0) { sn_s = a; sl2_s = b; }
    }
    __syncthreads();

    if (threadIdx.x < 256) {
        const float Sf = red[0][t] + red[1][t] + red[2][t] + red[3][t];
        const float n  = sn_s;
        const float cc = centers[c * FEAT + t];
        out[1 + c * FEAT + t] = cc + ALPHA * (Sf - n * cc) / (1.f + n);
        float part = 0.5f * n * cc * cc - Sf * cc;
        for (int off = 32; off; off >>= 1) part += __shfl_down(part, off, 64);
        if ((t & 63) == 0) r2[t >> 6] = part;
    }
    __syncthreads();

    if (threadIdx.x == 0) {
        const float my = r2[0] + r2[1] + r2[2] + r2[3] + 0.5f * sl2_s;
        atomicAdd(loss_acc, my);          // device-scope
        __threadfence();
        const int old = atomicAdd(done, 1);
        if (old == NCLS - 1) {
            // all 86 loss-adds precede their done-adds -> total is final
            out[0] = atomicAdd(loss_acc, 0.f);
        }
    }
}

extern "C" void kernel_launch(void* const* d_in, const int* in_sizes, int n_in,
                              void* d_out, int out_size, void* d_ws, size_t ws_size,
                              hipStream_t stream)
{
    const float* feat    = (const float*)d_in[0];
    const int*   labels  = (const int*)d_in[1];
    const float* centers = (const float*)d_in[2];
    float* out = (float*)d_out;
    float* ws  = (float*)d_ws;

    float* S_part   = ws + WS_S;
    float* cnt_part = ws + WS_CNT;
    float* l2_part  = ws + WS_L2;
    float* loss_acc = ws + WS_LOSS;
    int*   done     = (int*)(ws + WS_DONE);

    ctc_main<<<NCLS * K / 2, 128, 0, stream>>>(
        (const float4*)feat, (const int4*)labels,
        (float4*)S_part, cnt_part, l2_part, loss_acc, done);

    ctc_finalize<<<NCLS, 1024, 0, stream>>>(
        centers, S_part, cnt_part, l2_part, loss_acc, done, out);
}

// Round 10
// 33.131 us; speedup vs baseline: 1.0364x; 1.0364x over previous
//
#include <hip/hip_runtime.h>

#define ALPHA 0.5f
#define NCLS 86
#define FEAT 256
#define NTOT 131072

constexpr int K  = 64;          // sample chunks
constexpr int CH = NTOT / K;    // 2048 samples per chunk (one wave each)
constexpr int L4 = CH / 4;      // 512 int4 label-packs per chunk

// ws layout (floats):
//   S_part   [NCLS][K][FEAT]  = 1409024
//   cnt_part [NCLS][K]        = 5504
//   l2_part  [NCLS][K]        = 5504
//   loss_acc                  = 1
//   done (int)                = 1
constexpr size_t WS_S    = 0;
constexpr size_t WS_CNT  = (size_t)NCLS * K * FEAT;
constexpr size_t WS_L2   = WS_CNT + (size_t)NCLS * K;
constexpr size_t WS_LOSS = WS_L2 + (size_t)NCLS * K;
constexpr size_t WS_DONE = WS_LOSS + 1;

// 128-thread blocks (2 waves): 2752 blocks = 10.75/CU, whole grid
// co-resident in one scheduling round (~21.5 waves/CU).
__global__ __launch_bounds__(128) void ctc_main(
    const float4* __restrict__ feat4, const int4* __restrict__ lab4,
    float4* __restrict__ S_part4, float* __restrict__ cnt_part,
    float* __restrict__ l2_part, float* __restrict__ loss_acc,
    int* __restrict__ done)
{
    // zero the finalize accumulators; every block writes the same values,
    // and stream order guarantees this precedes all ctc_finalize blocks.
    if (threadIdx.x == 0) { *loss_acc = 0.f; *done = 0; }

    const int wave = threadIdx.x >> 6;
    const int lane = threadIdx.x & 63;
    const int pair = blockIdx.x * 2 + wave;   // = c*K + k
    const int k = pair & (K - 1);
    const int c = pair / K;
    const int base = k * CH;                  // first sample of this chunk

    const int4* lp = lab4 + (base >> 2) + lane;
    // dummy row for empty-mask slots: chunk's own row 0 (L2-hot after 1st touch)
    const size_t dummy = (size_t)base * 64 + lane;

    float4 acc = {0.f, 0.f, 0.f, 0.f};
    float  acc2 = 0.f;
    int    cnt  = 0;   // wave-uniform (ballot popcounts)

    int4 L = lp[0];    // prefetched labels for current iteration
    for (int it = 0; it < L4; it += 64) {
        const int4 Lc = L;
        if (it + 64 < L4) L = lp[it + 64];    // prefetch next iter's labels
        unsigned long long m0 = __ballot(Lc.x == c);
        unsigned long long m1 = __ballot(Lc.y == c);
        unsigned long long m2 = __ballot(Lc.z == c);
        unsigned long long m3 = __ballot(Lc.w == c);
        cnt += __popcll(m0) + __popcll(m1) + __popcll(m2) + __popcll(m3);

        // cross-mask 4-wide drain: pop one bit from EACH mask per trip and
        // issue all 4 row-loads before any accumulate (~3 useful loads in
        // flight typical; empty slots re-read the L2-hot dummy row).
#define ACCUM(v)                                                           \
        { acc.x += v.x; acc.y += v.y; acc.z += v.z; acc.w += v.w;          \
          acc2  += v.x * v.x + v.y * v.y + v.z * v.z + v.w * v.w; }
        while (m0 | m1 | m2 | m3) {
            const bool h0 = m0 != 0, h1 = m1 != 0, h2 = m2 != 0, h3 = m3 != 0;
            const int b0 = (int)__ffsll((long long)m0) - 1;
            const int b1 = (int)__ffsll((long long)m1) - 1;
            const int b2 = (int)__ffsll((long long)m2) - 1;
            const int b3 = (int)__ffsll((long long)m3) - 1;
            m0 &= m0 - 1; m1 &= m1 - 1; m2 &= m2 - 1; m3 &= m3 - 1;
            const float4 v0 = feat4[h0 ? (size_t)(base + (it + b0) * 4 + 0) * 64 + lane : dummy];
            const float4 v1 = feat4[h1 ? (size_t)(base + (it + b1) * 4 + 1) * 64 + lane : dummy];
            const float4 v2 = feat4[h2 ? (size_t)(base + (it + b2) * 4 + 2) * 64 + lane : dummy];
            const float4 v3 = feat4[h3 ? (size_t)(base + (it + b3) * 4 + 3) * 64 + lane : dummy];
            if (h0) ACCUM(v0)
            if (h1) ACCUM(v1)
            if (h2) ACCUM(v2)
            if (h3) ACCUM(v3)
        }
#undef ACCUM
    }

    // acc holds features 4*lane .. 4*lane+3 -> write partial row directly
    S_part4[(size_t)pair * 64 + lane] = acc;

    for (int off = 32; off; off >>= 1)
        acc2 += __shfl_down(acc2, off, 64);
    if (lane == 0) {
        cnt_part[pair] = (float)cnt;
        l2_part[pair]  = acc2;
    }
}

__global__ __launch_bounds__(1024) void ctc_finalize(
    const float* __restrict__ centers, const float* __restrict__ S_part,
    const float* __restrict__ cnt_part, const float* __restrict__ l2_part,
    float* __restrict__ loss_acc, int* __restrict__ done,
    float* __restrict__ out)   // out[0] = loss, out+1 = new centers
{
    const int c  = blockIdx.x;
    const int t  = threadIdx.x & 255;
    const int kq = threadIdx.x >> 8;     // 0..3, k-quarter

    float S = 0.f;
#pragma unroll
    for (int j = 0; j < K / 4; ++j)
        S += S_part[((size_t)c * K + kq * (K / 4) + j) * FEAT + t];

    __shared__ float red[4][FEAT];
    __shared__ float r2[4];
    __shared__ float sn_s, sl2_s;
    red[kq][t] = S;

    if (threadIdx.x < 64) {
        float a = cnt_part[c * K + threadIdx.x];
        float b = l2_part[c * K + threadIdx.x];
        for (int off = 32; off; off >>= 1) {
            a += __shfl_down(a, off, 64);
            b += __shfl_down(b, off, 64);
        }
        if (threadIdx.x == 0) { sn_s = a; sl2_s = b; }
    }
    __syncthreads();

    if (threadIdx.x < 256) {
        const float Sf = red[0][t] + red[1][t] + red[2][t] + red[3][t];
        const float n  = sn_s;
        const float cc = centers[c * FEAT + t];
        out[1 + c * FEAT + t] = cc + ALPHA * (Sf - n * cc) / (1.f + n);
        float part = 0.5f * n * cc * cc - Sf * cc;
        for (int off = 32; off; off >>= 1) part += __shfl_down(part, off, 64);
        if ((t & 63) == 0) r2[t >> 6] = part;
    }
    __syncthreads();

    if (threadIdx.x == 0) {
        const float my = r2[0] + r2[1] + r2[2] + r2[3] + 0.5f * sl2_s;
        atomicAdd(loss_acc, my);          // device-scope
        __threadfence();
        const int old = atomicAdd(done, 1);
        if (old == NCLS - 1) {
            // all 86 loss-adds precede their done-adds -> total is final
            out[0] = atomicAdd(loss_acc, 0.f);
        }
    }
}

extern "C" void kernel_launch(void* const* d_in, const int* in_sizes, int n_in,
                              void* d_out, int out_size, void* d_ws, size_t ws_size,
                              hipStream_t stream)
{
    const float* feat    = (const float*)d_in[0];
    const int*   labels  = (const int*)d_in[1];
    const float* centers = (const float*)d_in[2];
    float* out = (float*)d_out;
    float* ws  = (float*)d_ws;

    float* S_part   = ws + WS_S;
    float* cnt_part = ws + WS_CNT;
    float* l2_part  = ws + WS_L2;
    float* loss_acc = ws + WS_LOSS;
    int*   done     = (int*)(ws + WS_DONE);

    ctc_main<<<NCLS * K / 2, 128, 0, stream>>>(
        (const float4*)feat, (const int4*)labels,
        (float4*)S_part, cnt_part, l2_part, loss_acc, done);

    ctc_finalize<<<NCLS, 1024, 0, stream>>>(
        centers, S_part, cnt_part, l2_part, loss_acc, done, out);
}

// Round 11
// 32.686 us; speedup vs baseline: 1.0505x; 1.0136x over previous
//
#include <hip/hip_runtime.h>

#define ALPHA 0.5f
#define NCLS 86
#define FEAT 256
#define NTOT 131072

constexpr int K  = 64;          // sample chunks
constexpr int CH = NTOT / K;    // 2048 samples per chunk (one wave each)
constexpr int L4 = CH / 4;      // 512 int4 label-packs per chunk

// ws layout (floats):
//   S_part   [NCLS][K][FEAT]  = 1409024
//   cnt_part [NCLS][K]        = 5504
//   l2_part  [NCLS][K]        = 5504
//   class_loss [NCLS]         = 86
constexpr size_t WS_S   = 0;
constexpr size_t WS_CNT = (size_t)NCLS * K * FEAT;
constexpr size_t WS_L2  = WS_CNT + (size_t)NCLS * K;
constexpr size_t WS_CLS = WS_L2 + (size_t)NCLS * K;

// 128-thread blocks (2 waves): 2752 blocks = 10.75/CU, whole grid
// co-resident in one scheduling round (~21.5 waves/CU).
__global__ __launch_bounds__(128) void ctc_main(
    const float4* __restrict__ feat4, const int4* __restrict__ lab4,
    float4* __restrict__ S_part4, float* __restrict__ cnt_part,
    float* __restrict__ l2_part)
{
    const int wave = threadIdx.x >> 6;
    const int lane = threadIdx.x & 63;
    const int pair = blockIdx.x * 2 + wave;   // = c*K + k
    const int k = pair % K;
    const int c = pair / K;
    const int base = k * CH;                  // first sample of this chunk

    const int4* lp = lab4 + (base >> 2) + lane;
    // dummy row for empty-mask slots: chunk's own row 0 (L2-hot after 1st touch)
    const size_t dummy = (size_t)base * 64 + lane;

    float4 acc = {0.f, 0.f, 0.f, 0.f};
    float  acc2 = 0.f;
    int    cnt  = 0;   // wave-uniform (ballot popcounts)

    int4 L = lp[0];    // prefetched labels for current iteration
    for (int it = 0; it < L4; it += 64) {
        const int4 Lc = L;
        if (it + 64 < L4) L = lp[it + 64];    // prefetch next iter's labels
        unsigned long long m0 = __ballot(Lc.x == c);
        unsigned long long m1 = __ballot(Lc.y == c);
        unsigned long long m2 = __ballot(Lc.z == c);
        unsigned long long m3 = __ballot(Lc.w == c);
        cnt += __popcll(m0) + __popcll(m1) + __popcll(m2) + __popcll(m3);

        // cross-mask 4-wide drain: pop one bit from EACH mask per trip and
        // issue all 4 row-loads before any accumulate (~3 useful loads in
        // flight typical; empty slots re-read the L2-hot dummy row).
#define ACCUM(v)                                                           \
        { acc.x += v.x; acc.y += v.y; acc.z += v.z; acc.w += v.w;          \
          acc2  += v.x * v.x + v.y * v.y + v.z * v.z + v.w * v.w; }
        while (m0 | m1 | m2 | m3) {
            const bool h0 = m0 != 0, h1 = m1 != 0, h2 = m2 != 0, h3 = m3 != 0;
            const int b0 = (int)__ffsll((long long)m0) - 1;
            const int b1 = (int)__ffsll((long long)m1) - 1;
            const int b2 = (int)__ffsll((long long)m2) - 1;
            const int b3 = (int)__ffsll((long long)m3) - 1;
            m0 &= m0 - 1; m1 &= m1 - 1; m2 &= m2 - 1; m3 &= m3 - 1;
            const float4 v0 = feat4[h0 ? (size_t)(base + (it + b0) * 4 + 0) * 64 + lane : dummy];
            const float4 v1 = feat4[h1 ? (size_t)(base + (it + b1) * 4 + 1) * 64 + lane : dummy];
            const float4 v2 = feat4[h2 ? (size_t)(base + (it + b2) * 4 + 2) * 64 + lane : dummy];
            const float4 v3 = feat4[h3 ? (size_t)(base + (it + b3) * 4 + 3) * 64 + lane : dummy];
            if (h0) ACCUM(v0)
            if (h1) ACCUM(v1)
            if (h2) ACCUM(v2)
            if (h3) ACCUM(v3)
        }
#undef ACCUM
    }

    // acc holds features 4*lane .. 4*lane+3 -> write partial row directly
    S_part4[(size_t)pair * 64 + lane] = acc;

    for (int off = 32; off; off >>= 1)
        acc2 += __shfl_down(acc2, off, 64);
    if (lane == 0) {
        cnt_part[pair] = (float)cnt;
        l2_part[pair]  = acc2;
    }
}

__global__ __launch_bounds__(1024) void ctc_finalize(
    const float* __restrict__ centers, const float* __restrict__ S_part,
    const float* __restrict__ cnt_part, const float* __restrict__ l2_part,
    float* __restrict__ class_loss, float* __restrict__ out_centers)
{
    const int c  = blockIdx.x;
    const int t  = threadIdx.x & 255;
    const int kq = threadIdx.x >> 8;     // 0..3, k-quarter

    float S = 0.f;
#pragma unroll
    for (int j = 0; j < 16; ++j)
        S += S_part[((size_t)c * K + kq * 16 + j) * FEAT + t];

    __shared__ float red[4][FEAT];
    __shared__ float r2[4];
    __shared__ float sn_s, sl2_s;
    red[kq][t] = S;

    if (threadIdx.x < 64) {
        float a = cnt_part[c * K + threadIdx.x];
        float b = l2_part[c * K + threadIdx.x];
        for (int off = 32; off; off >>= 1) {
            a += __shfl_down(a, off, 64);
            b += __shfl_down(b, off, 64);
        }
        if (threadIdx.x == 0) { sn_s = a; sl2_s = b; }
    }
    __syncthreads();

    if (threadIdx.x < 256) {
        const float Sf = red[0][t] + red[1][t] + red[2][t] + red[3][t];
        const float n  = sn_s;
        const float cc = centers[c * FEAT + t];
        out_centers[c * FEAT + t] = cc + ALPHA * (Sf - n * cc) / (1.f + n);
        float part = 0.5f * n * cc * cc - Sf * cc;
        for (int off = 32; off; off >>= 1) part += __shfl_down(part, off, 64);
        if ((t & 63) == 0) r2[t >> 6] = part;
    }
    __syncthreads();
    if (threadIdx.x == 0)
        class_loss[c] = r2[0] + r2[1] + r2[2] + r2[3] + 0.5f * sl2_s;
}

__global__ void ctc_loss_write(const float* __restrict__ class_loss,
                               float* __restrict__ out)
{
    const int l = threadIdx.x;   // 64 threads, one wave
    float v = (l < NCLS) ? class_loss[l] : 0.f;
    if (l + 64 < NCLS) v += class_loss[l + 64];
    for (int off = 32; off; off >>= 1) v += __shfl_down(v, off, 64);
    if (l == 0) out[0] = v;
}

extern "C" void kernel_launch(void* const* d_in, const int* in_sizes, int n_in,
                              void* d_out, int out_size, void* d_ws, size_t ws_size,
                              hipStream_t stream)
{
    const float* feat    = (const float*)d_in[0];
    const int*   labels  = (const int*)d_in[1];
    const float* centers = (const float*)d_in[2];
    float* out = (float*)d_out;
    float* ws  = (float*)d_ws;

    float* S_part     = ws + WS_S;
    float* cnt_part   = ws + WS_CNT;
    float* l2_part    = ws + WS_L2;
    float* class_loss = ws + WS_CLS;

    ctc_main<<<NCLS * K / 2, 128, 0, stream>>>(
        (const float4*)feat, (const int4*)labels,
        (float4*)S_part, cnt_part, l2_part);

    ctc_finalize<<<NCLS, 1024, 0, stream>>>(
        centers, S_part, cnt_part, l2_part, class_loss, out + 1);

    ctc_loss_write<<<1, 64, 0, stream>>>(class_loss, out);
}